// Round 1
// baseline (472.356 us; speedup 1.0000x reference)
//
#include <hip/hip_runtime.h>
#include <math.h>
#include <stdint.h>

// KWinners: per-row top-K binary mask with duty-cycle boosting.
// x: (4096, 16384) fp32, duty: (16384,) fp32, out: (4096, 16384) fp32 0/1 mask.
// Exact top-K per row via 3-pass LDS radix select on order-preserving u32 keys,
// ties at the K-th value broken by lowest index (jax.lax.top_k semantics).

#define N_UNITS 16384
#define K_WIN 655
#define NT 512          // threads per block (8 waves)
#define BINS0 2048      // 11-bit digit histogram
#define CAND_CAP 1024   // pass-1 candidate list capacity
#define EQ_CAP 256      // ==threshold list capacity

// Order-preserving float -> uint map: larger float => larger key.
__device__ __forceinline__ uint32_t fkey(float f) {
    uint32_t b = __float_as_uint(f);
    uint32_t m = (uint32_t)((int32_t)b >> 31) | 0x80000000u;
    return b ^ m;
}

__global__ void boost_kernel(const float* __restrict__ duty,
                             float* __restrict__ bf, int n) {
    int i = blockIdx.x * blockDim.x + threadIdx.x;
    if (i < n) {
        const float td = 0.03997802734375f;  // 655/16384, exact in fp32
        float s = td - duty[i];              // fp32 subtract, matches ref
        bf[i] = (float)exp((double)s);       // correctly-rounded fp32 exp
    }
}

// Find bin d such that (count in bins > d) < krem <= (count in bins >= d).
// Writes d to *sc_d and (krem - count_above_d) to *sc_k. All threads call.
__device__ __forceinline__ void select_bin(const uint32_t* hist, int nbins,
                                           uint32_t krem,
                                           volatile uint32_t* wsum,
                                           uint32_t* sc_d, uint32_t* sc_k) {
    const int tid = threadIdx.x;
    const int lane = tid & 63;
    const int w = tid >> 6;
    const int cper = nbins / NT;
    const int base = tid * cper;
    uint32_t s = 0;
#pragma unroll
    for (int c = 0; c < cper; ++c) s += hist[base + c];
    // wave-level inclusive suffix scan (lanes >= lane)
    uint32_t v = s;
#pragma unroll
    for (int off = 1; off < 64; off <<= 1) {
        uint32_t o = __shfl_down(v, off, 64);
        if (lane + off < 64) v += o;
    }
    if (lane == 0) wsum[w] = v;
    __syncthreads();
    uint32_t above = 0;
#pragma unroll
    for (int ww = 0; ww < 8; ++ww)
        if (ww > w) above += wsum[ww];
    uint32_t H = (v - s) + above;  // count in bins above this thread's chunk
    if (H < krem && H + s >= krem) {
        uint32_t acc = H;
        for (int c = cper - 1; c >= 0; --c) {
            uint32_t h = hist[base + c];
            if (acc + h >= krem) {
                *sc_d = (uint32_t)(base + c);
                *sc_k = krem - acc;
                break;
            }
            acc += h;
        }
    }
    __syncthreads();
}

__global__ __launch_bounds__(NT, 4) void kwinners_kernel(
    const float* __restrict__ x, const float* __restrict__ bf,
    float* __restrict__ out) {
    __shared__ uint32_t keys[N_UNITS];   // 64 KB
    __shared__ uint32_t hist[BINS0];     // 8 KB
    __shared__ uint32_t wsum[8];
    __shared__ uint32_t cand[CAND_CAP];  // 4 KB
    __shared__ uint32_t eqi[EQ_CAP];     // 1 KB
    __shared__ uint32_t sc[8];           // 0:cand_cnt 1:eq_cnt 2:d_sel 3:krem

    const int tid = threadIdx.x;
    const int row = blockIdx.x;
    const float4* xrow = (const float4*)(x + (size_t)row * N_UNITS);
    const float4* bfv = (const float4*)bf;
    float4* orow = (float4*)(out + (size_t)row * N_UNITS);

    for (int b = tid; b < BINS0; b += NT) hist[b] = 0;
    if (tid < 8) sc[tid] = 0;
    __syncthreads();

    // ---- load + key transform + pass-0 histogram (bits 31..21), fused ----
#pragma unroll
    for (int j = 0; j < N_UNITS / (NT * 4); ++j) {
        int i4 = tid + j * NT;
        float4 xv = xrow[i4];
        float4 bv = bfv[i4];
        uint4 k;
        k.x = fkey(xv.x * bv.x);
        k.y = fkey(xv.y * bv.y);
        k.z = fkey(xv.z * bv.z);
        k.w = fkey(xv.w * bv.w);
        ((uint4*)keys)[i4] = k;
        atomicAdd(&hist[k.x >> 21], 1u);
        atomicAdd(&hist[k.y >> 21], 1u);
        atomicAdd(&hist[k.z >> 21], 1u);
        atomicAdd(&hist[k.w >> 21], 1u);
    }
    __syncthreads();

    uint32_t krem = K_WIN;
    select_bin(hist, BINS0, krem, wsum, &sc[2], &sc[3]);
    const uint32_t d0 = sc[2];
    krem = sc[3];
    __syncthreads();

    // ---- pass 1: elements with top-11 == d0; histogram bits 20..10 ----
    for (int b = tid; b < BINS0; b += NT) hist[b] = 0;
    __syncthreads();
#pragma unroll
    for (int j = 0; j < N_UNITS / (NT * 4); ++j) {
        int i4 = tid + j * NT;
        uint4 k = ((const uint4*)keys)[i4];
        int ib = i4 * 4;
        if ((k.x >> 21) == d0) {
            atomicAdd(&hist[(k.x >> 10) & 0x7FF], 1u);
            uint32_t p = atomicAdd(&sc[0], 1u);
            if (p < CAND_CAP) cand[p] = (uint32_t)(ib + 0);
        }
        if ((k.y >> 21) == d0) {
            atomicAdd(&hist[(k.y >> 10) & 0x7FF], 1u);
            uint32_t p = atomicAdd(&sc[0], 1u);
            if (p < CAND_CAP) cand[p] = (uint32_t)(ib + 1);
        }
        if ((k.z >> 21) == d0) {
            atomicAdd(&hist[(k.z >> 10) & 0x7FF], 1u);
            uint32_t p = atomicAdd(&sc[0], 1u);
            if (p < CAND_CAP) cand[p] = (uint32_t)(ib + 2);
        }
        if ((k.w >> 21) == d0) {
            atomicAdd(&hist[(k.w >> 10) & 0x7FF], 1u);
            uint32_t p = atomicAdd(&sc[0], 1u);
            if (p < CAND_CAP) cand[p] = (uint32_t)(ib + 3);
        }
    }
    __syncthreads();
    select_bin(hist, BINS0, krem, wsum, &sc[2], &sc[3]);
    const uint32_t d1 = sc[2];
    krem = sc[3];
    const uint32_t ncand = sc[0];
    __syncthreads();

    // ---- pass 2: elements with top-22 == (d0<<11)|d1; histogram bits 9..0 ----
    const uint32_t pfx21 = (d0 << 11) | d1;  // top 22 bits of key, right-aligned
    for (int b = tid; b < 1024; b += NT) hist[b] = 0;
    __syncthreads();
    if (ncand <= CAND_CAP) {
        for (uint32_t j = tid; j < ncand; j += NT) {
            uint32_t k = keys[cand[j]];
            if ((k >> 10) == pfx21) atomicAdd(&hist[k & 0x3FF], 1u);
        }
    } else {  // candidate list overflowed: full rescan (rare)
#pragma unroll
        for (int j = 0; j < N_UNITS / (NT * 4); ++j) {
            int i4 = tid + j * NT;
            uint4 k = ((const uint4*)keys)[i4];
            if ((k.x >> 10) == pfx21) atomicAdd(&hist[k.x & 0x3FF], 1u);
            if ((k.y >> 10) == pfx21) atomicAdd(&hist[k.y & 0x3FF], 1u);
            if ((k.z >> 10) == pfx21) atomicAdd(&hist[k.z & 0x3FF], 1u);
            if ((k.w >> 10) == pfx21) atomicAdd(&hist[k.w & 0x3FF], 1u);
        }
    }
    __syncthreads();
    select_bin(hist, 1024, krem, wsum, &sc[2], &sc[3]);
    const uint32_t d2 = sc[2];
    const uint32_t need = sc[3];  // winners among keys == T, lowest index first
    __syncthreads();

    const uint32_t T = (pfx21 << 10) | d2;  // exact K-th largest key

    // ---- output: coalesced mask write; gather ==T indices ----
#pragma unroll
    for (int j = 0; j < N_UNITS / (NT * 4); ++j) {
        int i4 = tid + j * NT;
        uint4 k = ((const uint4*)keys)[i4];
        float4 o;
        o.x = (k.x > T) ? 1.0f : 0.0f;
        o.y = (k.y > T) ? 1.0f : 0.0f;
        o.z = (k.z > T) ? 1.0f : 0.0f;
        o.w = (k.w > T) ? 1.0f : 0.0f;
        orow[i4] = o;
        int ib = i4 * 4;
        if (k.x == T) {
            uint32_t p = atomicAdd(&sc[1], 1u);
            if (p < EQ_CAP) eqi[p] = (uint32_t)(ib + 0);
        }
        if (k.y == T) {
            uint32_t p = atomicAdd(&sc[1], 1u);
            if (p < EQ_CAP) eqi[p] = (uint32_t)(ib + 1);
        }
        if (k.z == T) {
            uint32_t p = atomicAdd(&sc[1], 1u);
            if (p < EQ_CAP) eqi[p] = (uint32_t)(ib + 2);
        }
        if (k.w == T) {
            uint32_t p = atomicAdd(&sc[1], 1u);
            if (p < EQ_CAP) eqi[p] = (uint32_t)(ib + 3);
        }
    }
    __syncthreads();

    // ---- tie fix-up: set 1.0 at the `need` lowest-index ==T elements ----
    const uint32_t ecnt = sc[1];
    float* orowf = (float*)orow;
    if (ecnt <= EQ_CAP) {
        for (uint32_t j = tid; j < ecnt; j += NT) {
            uint32_t idx = eqi[j];
            uint32_t rank = 0;
            for (uint32_t m = 0; m < ecnt; ++m) rank += (eqi[m] < idx) ? 1u : 0u;
            if (rank < need) orowf[idx] = 1.0f;
        }
    } else if (tid == 0) {  // pathological tie count: serial, effectively never
        uint32_t r = 0;
        for (int i = 0; i < N_UNITS && r < need; ++i)
            if (keys[i] == T) {
                orowf[i] = 1.0f;
                ++r;
            }
    }
}

extern "C" void kernel_launch(void* const* d_in, const int* in_sizes, int n_in,
                              void* d_out, int out_size, void* d_ws,
                              size_t ws_size, hipStream_t stream) {
    const float* x = (const float*)d_in[0];
    const float* duty = (const float*)d_in[1];
    float* out = (float*)d_out;
    float* bf = (float*)d_ws;  // 16384 floats = 64 KB scratch

    hipLaunchKernelGGL(boost_kernel, dim3(N_UNITS / 256), dim3(256), 0, stream,
                       duty, bf, N_UNITS);
    int rows = out_size / N_UNITS;  // 4096
    hipLaunchKernelGGL(kwinners_kernel, dim3(rows), dim3(NT), 0, stream, x, bf,
                       out);
}

// Round 2
// 451.423 us; speedup vs baseline: 1.0464x; 1.0464x over previous
//
#include <hip/hip_runtime.h>
#include <math.h>
#include <stdint.h>

// KWinners: per-row top-K binary mask with duty-cycle boosting.
// x: (4096, 16384) fp32, duty: (16384,) fp32, out: (4096, 16384) fp32 0/1 mask.
//
// Round-2 design: contention-free probe counting on 16-bit key prefixes.
//  - khi (top 16 bits of order-preserving key) in LDS: 32 KB -> 3 blocks/CU.
//  - Fused load: 11 register counters #(khi > P_j), no atomics at all.
//  - Bracket the K-th khi; gather candidates; exact rank on full keys with
//    (key desc, idx asc) tie-break = jax.lax.top_k semantics.
//  - Refinement loop + serial radix fallback keep it exact for ANY input.

#define N_UNITS 16384
#define K_WIN 655
#define NT 512
#define NPROBE 11
#define CAP 2048

// Order-preserving float -> uint map: larger float => larger key.
__device__ __forceinline__ uint32_t fkey(float f) {
    uint32_t b = __float_as_uint(f);
    uint32_t m = (uint32_t)((int32_t)b >> 31) | 0x80000000u;
    return b ^ m;
}

__global__ void boost_kernel(const float* __restrict__ duty,
                             float* __restrict__ bf, int n) {
    int i = blockIdx.x * blockDim.x + threadIdx.x;
    if (i < n) {
        const float td = 0.03997802734375f;  // 655/16384, exact in fp32
        float s = td - duty[i];              // fp32 subtract, matches ref
        bf[i] = (float)exp((double)s);       // correctly-rounded fp32 exp
    }
}

__global__ __launch_bounds__(NT, 6) void kwinners_kernel(
    const float* __restrict__ x, const float* __restrict__ bf,
    float* __restrict__ out) {
    __shared__ __align__(16) uint32_t khiw[N_UNITS / 2];  // 32 KB, 2 khi/word
    __shared__ uint32_t red[(NT / 64) * NPROBE];          // per-wave counts
    __shared__ int cglob[NPROBE];
    __shared__ uint32_t cand_idx[CAP];  // 8 KB
    __shared__ uint32_t cand_key[CAP];  // 8 KB
    __shared__ int prb[NPROBE];
    __shared__ int sc[2];  // 0: candidate count

    const int tid = threadIdx.x;
    const int lane = tid & 63;
    const int w = tid >> 6;
    const int row = blockIdx.x;
    const float4* xrow = (const float4*)(x + (size_t)row * N_UNITS);
    const float4* bfv = (const float4*)bf;
    float* orow = out + (size_t)row * N_UNITS;

    // Probes tuned for N(0,1)*boost: row thresholds concentrate near 1.20.
    if (tid < NPROBE) {
        const float pv[NPROBE] = {1.90f, 1.70f, 1.55f, 1.43f, 1.33f, 1.25f,
                                  1.18f, 1.12f, 1.06f, 0.99f, 0.90f};
        prb[tid] = (int)(fkey(pv[tid]) >> 16);
    }
    if (tid == 0) sc[0] = 0;
    __syncthreads();

    int P[NPROBE];
#pragma unroll
    for (int p = 0; p < NPROBE; ++p) P[p] = prb[p];
    int cnt[NPROBE];
#pragma unroll
    for (int p = 0; p < NPROBE; ++p) cnt[p] = 0;

    // ---- fused: global load -> keys -> khi to LDS + probe counting ----
#pragma unroll
    for (int j = 0; j < N_UNITS / (NT * 4); ++j) {  // 8 iters
        int i4 = tid + j * NT;
        float4 xv = xrow[i4];
        float4 bv = bfv[i4];
        int h0 = (int)(fkey(xv.x * bv.x) >> 16);
        int h1 = (int)(fkey(xv.y * bv.y) >> 16);
        int h2 = (int)(fkey(xv.z * bv.z) >> 16);
        int h3 = (int)(fkey(xv.w * bv.w) >> 16);
        uint2 pk;
        pk.x = (uint32_t)h0 | ((uint32_t)h1 << 16);
        pk.y = (uint32_t)h2 | ((uint32_t)h3 << 16);
        ((uint2*)khiw)[i4] = pk;
#pragma unroll
        for (int p = 0; p < NPROBE; ++p)
            cnt[p] += (h0 > P[p]) + (h1 > P[p]) + (h2 > P[p]) + (h3 > P[p]);
    }

    // ---- block reduction of probe counters -> cglob ----
    auto reduce_counts = [&]() {
#pragma unroll
        for (int p = 0; p < NPROBE; ++p) {
            int v = cnt[p];
#pragma unroll
            for (int m = 32; m >= 1; m >>= 1) v += __shfl_xor(v, m, 64);
            if (lane == 0) red[w * NPROBE + p] = (uint32_t)v;
        }
        __syncthreads();
        if (tid < NPROBE) {
            int s = 0;
#pragma unroll
            for (int ww = 0; ww < NT / 64; ++ww) s += (int)red[ww * NPROBE + tid];
            cglob[tid] = s;
        }
        __syncthreads();
    };
    reduce_counts();

    // ---- bracket (lo, hi]: count(>hi) < K <= count(>lo) ----
    int lo, hi, cab, cgl;  // cab = count(>hi), cgl = count(>lo)
    {
        int j = 0;
        while (j < NPROBE && cglob[j] < K_WIN) ++j;
        if (j == 0) {
            lo = P[0]; cgl = cglob[0]; hi = 65535; cab = 0;
        } else if (j == NPROBE) {
            lo = -1; cgl = N_UNITS; hi = P[NPROBE - 1]; cab = cglob[NPROBE - 1];
        } else {
            lo = P[j]; cgl = cglob[j]; hi = P[j - 1]; cab = cglob[j - 1];
        }
    }
    int m = cgl - cab;

    // ---- refinement (exact, terminates; ~never runs on benchmark data) ----
    while (m > CAP && (hi - lo) > 1) {
        __syncthreads();
        if (tid < NPROBE)
            prb[tid] = lo + (int)(((long)(hi - lo) * (NPROBE - tid)) / (NPROBE + 1));
        __syncthreads();
#pragma unroll
        for (int p = 0; p < NPROBE; ++p) P[p] = prb[p];
#pragma unroll
        for (int p = 0; p < NPROBE; ++p) cnt[p] = 0;
        for (int j = 0; j < 4; ++j) {
            uint4 wv = ((const uint4*)khiw)[tid + j * NT];
            int h0 = (int)(wv.x & 0xFFFFu), h1 = (int)(wv.x >> 16);
            int h2 = (int)(wv.y & 0xFFFFu), h3 = (int)(wv.y >> 16);
            int h4 = (int)(wv.z & 0xFFFFu), h5 = (int)(wv.z >> 16);
            int h6 = (int)(wv.w & 0xFFFFu), h7 = (int)(wv.w >> 16);
#pragma unroll
            for (int p = 0; p < NPROBE; ++p)
                cnt[p] += (h0 > P[p]) + (h1 > P[p]) + (h2 > P[p]) + (h3 > P[p]) +
                          (h4 > P[p]) + (h5 > P[p]) + (h6 > P[p]) + (h7 > P[p]);
        }
        reduce_counts();
        int j = 0;
        while (j < NPROBE && cglob[j] < K_WIN) ++j;
        if (j == 0) {
            lo = P[0]; cgl = cglob[0];  // hi, cab unchanged
        } else if (j == NPROBE) {
            hi = P[NPROBE - 1]; cab = cglob[NPROBE - 1];  // lo, cgl unchanged
        } else {
            lo = P[j]; cgl = cglob[j]; hi = P[j - 1]; cab = cglob[j - 1];
        }
        m = cgl - cab;
    }

    // ---- gather candidates: khi in (lo, hi] ----
    for (int j = 0; j < 4; ++j) {
        int q = tid + j * NT;
        uint4 wv = ((const uint4*)khiw)[q];
        int base = q * 8;
        int h[8] = {(int)(wv.x & 0xFFFFu), (int)(wv.x >> 16),
                    (int)(wv.y & 0xFFFFu), (int)(wv.y >> 16),
                    (int)(wv.z & 0xFFFFu), (int)(wv.z >> 16),
                    (int)(wv.w & 0xFFFFu), (int)(wv.w >> 16)};
#pragma unroll
        for (int e = 0; e < 8; ++e) {
            if (h[e] > lo && h[e] <= hi) {
                int p = atomicAdd(&sc[0], 1);
                if (p < CAP) cand_idx[p] = (uint32_t)(base + e);
            }
        }
    }
    __syncthreads();
    const int mm = sc[0];
    const int need = K_WIN - cab;

    // ---- fetch full keys for candidates (scattered, L2/L3-hit) ----
    const float* xr = x + (size_t)row * N_UNITS;
    const int mc = (mm <= CAP) ? mm : 0;
    for (int j = tid; j < mc; j += NT) {
        int i = (int)cand_idx[j];
        cand_key[j] = fkey(xr[i] * bf[i]);
    }

    // ---- bulk mask write from khi (coalesced float4) ----
    for (int j = 0; j < N_UNITS / (NT * 4); ++j) {
        int f = tid + j * NT;
        uint2 wv = ((const uint2*)khiw)[f];
        float4 o;
        o.x = ((int)(wv.x & 0xFFFFu) > hi) ? 1.0f : 0.0f;
        o.y = ((int)(wv.x >> 16) > hi) ? 1.0f : 0.0f;
        o.z = ((int)(wv.y & 0xFFFFu) > hi) ? 1.0f : 0.0f;
        o.w = ((int)(wv.y >> 16) > hi) ? 1.0f : 0.0f;
        ((float4*)orow)[f] = o;
    }
    __syncthreads();  // orders cand_key writes AND bulk global writes

    if (mm <= CAP) {
        // ---- exact rank among candidates; scatter the `need` winners ----
        for (int j = tid; j < mm; j += NT) {
            uint32_t myk = cand_key[j];
            uint32_t myi = cand_idx[j];
            int r = 0;
            for (int l = 0; l < mm; ++l) {
                uint32_t lk = cand_key[l];
                r += (lk > myk) || (lk == myk && cand_idx[l] < myi);
            }
            if (r < need) orow[myi] = 1.0f;
        }
    } else if (tid == 0) {
        // Fallback (unreachable on benchmark data): > CAP ties at khi == hi.
        // Serial radix on low 16 bits of the full key; exact, index-ordered.
        uint32_t* h8 = cand_idx;  // reuse as 256-entry histogram
        for (int b = 0; b < 256; ++b) h8[b] = 0;
        for (int i = 0; i < N_UNITS; ++i) {
            int h = (int)((khiw[i >> 1] >> ((i & 1) * 16)) & 0xFFFFu);
            if (h == hi) h8[(fkey(xr[i] * bf[i]) & 0xFFFFu) >> 8]++;
        }
        int acc = 0, d1 = 0, need2 = 0;
        for (int b = 255; b >= 0; --b) {
            int c = (int)h8[b];
            if (acc + c >= need) { d1 = b; need2 = need - acc; break; }
            acc += c;
        }
        for (int b = 0; b < 256; ++b) h8[b] = 0;
        for (int i = 0; i < N_UNITS; ++i) {
            int h = (int)((khiw[i >> 1] >> ((i & 1) * 16)) & 0xFFFFu);
            if (h == hi) {
                uint32_t kl = fkey(xr[i] * bf[i]) & 0xFFFFu;
                if ((int)(kl >> 8) == d1) h8[kl & 0xFFu]++;
            }
        }
        int acc2 = 0, d2 = 0, need3 = 0;
        for (int b = 255; b >= 0; --b) {
            int c = (int)h8[b];
            if (acc2 + c >= need2) { d2 = b; need3 = need2 - acc2; break; }
            acc2 += c;
        }
        uint32_t Tlo = ((uint32_t)d1 << 8) | (uint32_t)d2;
        int r = 0;
        for (int i = 0; i < N_UNITS; ++i) {
            int h = (int)((khiw[i >> 1] >> ((i & 1) * 16)) & 0xFFFFu);
            if (h == hi) {
                uint32_t kl = fkey(xr[i] * bf[i]) & 0xFFFFu;
                if (kl > Tlo) orow[i] = 1.0f;
                else if (kl == Tlo && r < need3) { orow[i] = 1.0f; ++r; }
            }
        }
    }
}

extern "C" void kernel_launch(void* const* d_in, const int* in_sizes, int n_in,
                              void* d_out, int out_size, void* d_ws,
                              size_t ws_size, hipStream_t stream) {
    const float* x = (const float*)d_in[0];
    const float* duty = (const float*)d_in[1];
    float* out = (float*)d_out;
    float* bf = (float*)d_ws;  // 16384 floats = 64 KB scratch

    hipLaunchKernelGGL(boost_kernel, dim3(N_UNITS / 256), dim3(256), 0, stream,
                       duty, bf, N_UNITS);
    int rows = out_size / N_UNITS;  // 4096
    hipLaunchKernelGGL(kwinners_kernel, dim3(rows), dim3(NT), 0, stream, x, bf,
                       out);
}